// Round 10
// baseline (87.495 us; speedup 1.0000x reference)
//
#include <hip/hip_runtime.h>
#include <math.h>

#define B_ROWS 8192
#define DIM 64
#define NCODES 2048
#define WAVES 8
#define ROWS_PER_BLOCK 32
#define CODES_PER_WAVE (NCODES / WAVES)      // 256 codes per wave
#define TILES_PER_WAVE (CODES_PER_WAVE / 16) // 16 tiles of 16 codes
#define EPSF 1e-6f
#define BETA 0.25f
#define V_VAL 0.125f                          // 1/sqrt(64)
#define LOSS_SCALE ((1.0f + BETA) / (float)B_ROWS)

typedef __attribute__((ext_vector_type(8))) short sh8;    // 8 bf16 = 4 VGPR
typedef __attribute__((ext_vector_type(4))) float f32x4;  // MFMA acc

__device__ __forceinline__ float wave_sum64(float v) {
#pragma unroll
    for (int m = 32; m >= 1; m >>= 1) v += __shfl_xor(v, m, 64);
    return v;
}

// RNE float -> bf16 bit trick (inputs finite)
__device__ __forceinline__ unsigned short f2bf(float f) {
    unsigned u = __float_as_uint(f);
    unsigned r = (u + 0x7fffu + ((u >> 16) & 1u)) >> 16;
    return (unsigned short)r;
}
__device__ __forceinline__ float bf2f(unsigned short h) {
    return __uint_as_float(((unsigned)h) << 16);
}

// Fragment layout (unchanged since round 0): frag #((tile16*3+split)*2+khalf)
// is 64 lanes x 16B; element (lane,j) = split_s(src[tile16*16+(lane&15)]
// [khalf*32+(lane>>4)*8+j]). Writer: tile=rc>>4, m=rc&15, h=dim>>5,
// q=(dim>>3)&3, j=dim&7, lane'=q*16+m.

// Kernel 1: code norms + bf16x3 code fragments (bit-identical math to R2-R9)
// + zeroes out_loss (stream order puts this before rq_fused's atomicAdds).
__global__ void rq_prep_codes(const float* __restrict__ codes,
                              float* __restrict__ cn,
                              unsigned short* __restrict__ cfrag,
                              float* __restrict__ out_loss) {
    int tid = threadIdx.x;
    int lane = tid & 63;                 // dim
    int c = blockIdx.x * 4 + (tid >> 6); // code
    if (blockIdx.x == 0 && tid == 0) *out_loss = 0.f;

    float cvv = codes[(size_t)c * DIM + lane];
    float s = wave_sum64(cvv * cvv);
    if (lane == 0) cn[c] = s;

    unsigned short s0 = f2bf(cvv);
    float rr = cvv - bf2f(s0);
    unsigned short s1 = f2bf(rr);
    rr -= bf2f(s1);
    unsigned short s2 = f2bf(rr);

    int ct = c >> 4, m = c & 15;
    int h = lane >> 5, q = (lane >> 3) & 3, j = lane & 7;
    int lanep = q * 16 + m;
    size_t base = ((size_t)(ct * 3) * 2 + h) * 512 + (size_t)lanep * 8 + j;
    cfrag[base] = s0;
    cfrag[base + 2 * 512] = s1;
    cfrag[base + 4 * 512] = s2;
}

// Kernel 2 (FUSED, round-9 shape + DEEP-PREFETCH P2): one block = 32 rows,
// 8 waves (512 thr), __launch_bounds__(512,2) -> arch-VGPR cap 256.
// Round-9 lesson: node-count gaps are ~0; overhead is fixed (fill + launch).
// Round-10 change (single variable): the 2-deep B ping-pong issued tile
// t+1's loads only ~120 cyc (one computeTile) before use vs ~200 cyc L2
// latency -> ~100 cyc visible stall per tile = the 2x gap between measured
// P2 (~13 us) and its issue/L2 floor (~6 us). Now: 4 named buffers,
// prefetch 3 tiles ahead (~360 cyc of cover). Live set ~216 VGPR < 256 cap
// at unchanged 2 waves/SIMD -> no spill by construction (round-7 lesson:
// spills only when cap < live set). MFMA order/scores/tie-break unchanged.
__global__ __launch_bounds__(512, 2) void rq_fused(
        const float* __restrict__ x,
        const float* __restrict__ pq,
        const float* __restrict__ codes,
        const float* __restrict__ cn,
        const unsigned short* __restrict__ cfrag,
        float* __restrict__ out_q,
        float* __restrict__ out_idx,
        float* __restrict__ out_loss) {
    __shared__ unsigned short afrag[12 * 512];                 // 12 KB
    __shared__ unsigned long long best[WAVES][ROWS_PER_BLOCK]; // 2 KB
    __shared__ float lpart[WAVES];

    int tid = threadIdx.x;
    int lane = tid & 63;
    int w = tid >> 6;                    // 0..7
    int r0 = blockIdx.x * ROWS_PER_BLOCK;

    float uvr[4], xvr[4], dr[4];

    // ---- P1: prep 4 rows per wave into LDS fragments ----
#pragma unroll
    for (int i = 0; i < 4; ++i) {
        int lr = w * 4 + i;
        int r = r0 + lr;
        float xv = x[(size_t)r * DIM + lane];
        float qv = pq[(size_t)r * DIM + lane];
        float n2 = wave_sum64(qv * qv);
        float inv = 1.0f / fmaxf(sqrtf(n2), EPSF);
        float uv = qv * inv;
        float d = V_VAL * wave_sum64(uv);
        float a = wave_sum64(uv * xv);
        float b = V_VAL * wave_sum64(xv);
        float den = 1.0f + d + EPSF;
        float cu = -b + (d * b - a) / den;
        float cv = a - (b - d * a) / den;
        float xcv = xv + uv * cu + V_VAL * cv;

        uvr[i] = uv; xvr[i] = xv; dr[i] = d;

        unsigned short s0 = f2bf(xcv);
        float rr = xcv - bf2f(s0);
        unsigned short s1 = f2bf(rr);
        rr -= bf2f(s1);
        unsigned short s2 = f2bf(rr);

        int rt = lr >> 4, m = lr & 15;
        int h = lane >> 5, q = (lane >> 3) & 3, j = lane & 7;
        int lanep = q * 16 + m;
        int base = ((rt * 3) * 2 + h) * 512 + lanep * 8 + j;
        afrag[base] = s0;
        afrag[base + 2 * 512] = s1;
        afrag[base + 4 * 512] = s2;
    }

    __syncthreads();

    // ---- P2: distance scan over this wave's 256-code range ----
    const sh8* lf = (const sh8*)afrag;
    const sh8* cf = (const sh8*)cfrag;

    sh8 afr[2][3][2];
#pragma unroll
    for (int rs = 0; rs < 2; ++rs)
#pragma unroll
        for (int s = 0; s < 3; ++s)
#pragma unroll
            for (int h = 0; h < 2; ++h)
                afr[rs][s][h] = lf[((rs * 3 + s) * 2 + h) * 64 + lane];

    int cbase = w * CODES_PER_WAVE;

    float bv[2][4];
    int bi[2][4];
#pragma unroll
    for (int rs = 0; rs < 2; ++rs)
#pragma unroll
        for (int i = 0; i < 4; ++i) { bv[rs][i] = INFINITY; bi[rs][i] = 0x7fffffff; }

    auto loadB = [&](sh8 (&Bf)[3][2], float& cnv, int t) {
        int ct = (cbase >> 4) + t;
#pragma unroll
        for (int s = 0; s < 3; ++s)
#pragma unroll
            for (int h = 0; h < 2; ++h)
                Bf[s][h] = cf[(size_t)((ct * 3 + s) * 2 + h) * 64 + lane];
        cnv = cn[cbase + t * 16 + (lane & 15)];
    };

    auto computeTile = [&](const sh8 (&Bf)[3][2], float cnv, int t) {
        f32x4 accA[2], accB[2];
#pragma unroll
        for (int rs = 0; rs < 2; ++rs) {
            accA[rs] = (f32x4){0.f, 0.f, 0.f, 0.f};
            accB[rs] = (f32x4){0.f, 0.f, 0.f, 0.f};
        }
        // 4 independent chains of depth 6 (2 rowsets x 2 K-halves),
        // smallest-weight products first (order validated rounds 3-9).
#pragma unroll
        for (int rs = 0; rs < 2; ++rs) {
            accA[rs] = __builtin_amdgcn_mfma_f32_16x16x32_bf16(afr[rs][2][0], Bf[0][0], accA[rs], 0, 0, 0);
            accB[rs] = __builtin_amdgcn_mfma_f32_16x16x32_bf16(afr[rs][2][1], Bf[0][1], accB[rs], 0, 0, 0);
            accA[rs] = __builtin_amdgcn_mfma_f32_16x16x32_bf16(afr[rs][1][0], Bf[1][0], accA[rs], 0, 0, 0);
            accB[rs] = __builtin_amdgcn_mfma_f32_16x16x32_bf16(afr[rs][1][1], Bf[1][1], accB[rs], 0, 0, 0);
            accA[rs] = __builtin_amdgcn_mfma_f32_16x16x32_bf16(afr[rs][0][0], Bf[2][0], accA[rs], 0, 0, 0);
            accB[rs] = __builtin_amdgcn_mfma_f32_16x16x32_bf16(afr[rs][0][1], Bf[2][1], accB[rs], 0, 0, 0);
            accA[rs] = __builtin_amdgcn_mfma_f32_16x16x32_bf16(afr[rs][1][0], Bf[0][0], accA[rs], 0, 0, 0);
            accB[rs] = __builtin_amdgcn_mfma_f32_16x16x32_bf16(afr[rs][1][1], Bf[0][1], accB[rs], 0, 0, 0);
            accA[rs] = __builtin_amdgcn_mfma_f32_16x16x32_bf16(afr[rs][0][0], Bf[1][0], accA[rs], 0, 0, 0);
            accB[rs] = __builtin_amdgcn_mfma_f32_16x16x32_bf16(afr[rs][0][1], Bf[1][1], accB[rs], 0, 0, 0);
            accA[rs] = __builtin_amdgcn_mfma_f32_16x16x32_bf16(afr[rs][0][0], Bf[0][0], accA[rs], 0, 0, 0);
            accB[rs] = __builtin_amdgcn_mfma_f32_16x16x32_bf16(afr[rs][0][1], Bf[0][1], accB[rs], 0, 0, 0);
        }
        int idxv = cbase + t * 16 + (lane & 15);
#pragma unroll
        for (int rs = 0; rs < 2; ++rs)
#pragma unroll
            for (int reg = 0; reg < 4; ++reg) {
                float sc = fmaf(-2.0f, accA[rs][reg] + accB[rs][reg], cnv);
                if (sc < bv[rs][reg]) { bv[rs][reg] = sc; bi[rs][reg] = idxv; }
            }
    };

    {
        // 4-buffer software pipeline, prefetch 3 tiles ahead.
        sh8 b0[3][2], b1[3][2], b2[3][2], b3[3][2];
        float c0, c1, c2, c3;
        loadB(b0, c0, 0);
        loadB(b1, c1, 1);
        loadB(b2, c2, 2);
        loadB(b3, c3, 3);
#pragma unroll 1
        for (int tt = 0; tt < TILES_PER_WAVE; tt += 4) {
            computeTile(b0, c0, tt);
            if (tt + 4 < TILES_PER_WAVE) loadB(b0, c0, tt + 4);
            computeTile(b1, c1, tt + 1);
            if (tt + 5 < TILES_PER_WAVE) loadB(b1, c1, tt + 5);
            computeTile(b2, c2, tt + 2);
            if (tt + 6 < TILES_PER_WAVE) loadB(b2, c2, tt + 6);
            computeTile(b3, c3, tt + 3);
            if (tt + 7 < TILES_PER_WAVE) loadB(b3, c3, tt + 7);
        }
    }

    // Per-row reduction across 16 cols -> this wave's best per local row.
    // row = rs*16 + (lane>>4)*4 + reg.
#pragma unroll
    for (int rs = 0; rs < 2; ++rs) {
#pragma unroll
        for (int reg = 0; reg < 4; ++reg) {
            float v = bv[rs][reg];
            int ix = bi[rs][reg];
#pragma unroll
            for (int m = 1; m < 16; m <<= 1) {
                float ov = __shfl_xor(v, m, 64);
                int oi = __shfl_xor(ix, m, 64);
                if (ov < v || (ov == v && oi < ix)) { v = ov; ix = oi; }
            }
            if ((lane & 15) == reg) {
                int lr = rs * 16 + (lane >> 4) * 4 + reg;
                unsigned u = __float_as_uint(v);
                unsigned k32 = (u & 0x80000000u) ? ~u : (u | 0x80000000u);
                best[w][lr] = ((unsigned long long)k32 << 32) |
                              (unsigned long long)(unsigned)ix;
            }
        }
    }

    __syncthreads();

    // ---- P3: combine 8 wave-partials per row + epilogue + in-block loss ----
    float lsum = 0.f;
#pragma unroll
    for (int i = 0; i < 4; ++i) {
        int lr = w * 4 + i;
        int r = r0 + lr;
        unsigned long long k = best[0][lr];
#pragma unroll
        for (int ww = 1; ww < WAVES; ++ww) {
            unsigned long long o = best[ww][lr];
            if (o < k) k = o;   // ranges w-ascending: global first-occurrence kept
        }
        int idx = (int)(unsigned)(k & 0xFFFFFFFFull);

        float qc = codes[(size_t)idx * DIM + lane];
        float aq = wave_sum64(uvr[i] * qc);
        float bq = V_VAL * wave_sum64(qc);
        float den = 1.0f + dr[i] + EPSF;
        float cu = bq + (dr[i] * bq - aq) / den;
        float cv = -aq - (bq - dr[i] * aq) / den;
        float qout = qc + uvr[i] * cu + V_VAL * cv;
        out_q[(size_t)r * DIM + lane] = qout;

        float diff = xvr[i] - qc;
        lsum += wave_sum64(diff * diff);
        if (lane == 0) out_idx[r] = (float)idx;
    }

    if (lane == 0) lpart[w] = lsum;
    __syncthreads();
    if (tid == 0) {
        float s = 0.f;
#pragma unroll
        for (int ww = 0; ww < WAVES; ++ww) s += lpart[ww];
        atomicAdd(out_loss, s * LOSS_SCALE);  // 256 adds total; no fences
    }
}

extern "C" void kernel_launch(void* const* d_in, const int* in_sizes, int n_in,
                              void* d_out, int out_size, void* d_ws, size_t ws_size,
                              hipStream_t stream) {
    const float* x     = (const float*)d_in[0];
    const float* pq    = (const float*)d_in[1];
    const float* codes = (const float*)d_in[2];

    float* out      = (float*)d_out;
    float* out_q    = out;                         // B*D
    float* out_idx  = out + (size_t)B_ROWS * DIM;  // B
    float* out_loss = out_idx + B_ROWS;            // 1

    char* ws = (char*)d_ws;
    float* cn            = (float*)ws;                          // 8 KB
    unsigned short* cfrg = (unsigned short*)(ws + 1024 * 1024); // 768 KB

    rq_prep_codes<<<NCODES / 4, 256, 0, stream>>>(codes, cn, cfrg, out_loss);
    rq_fused<<<B_ROWS / ROWS_PER_BLOCK, 512, 0, stream>>>(
        x, pq, codes, cn, cfrg, out_q, out_idx, out_loss);
}

// Round 11
// 83.020 us; speedup vs baseline: 1.0539x; 1.0539x over previous
//
#include <hip/hip_runtime.h>
#include <math.h>

#define B_ROWS 8192
#define DIM 64
#define NCODES 2048
#define WAVES 8
#define ROWS_PER_BLOCK 32
#define CODES_PER_WAVE (NCODES / WAVES)      // 256 codes per wave
#define TILES_PER_WAVE (CODES_PER_WAVE / 16) // 16 tiles of 16 codes
#define EPSF 1e-6f
#define BETA 0.25f
#define V_VAL 0.125f                          // 1/sqrt(64)
#define LOSS_SCALE ((1.0f + BETA) / (float)B_ROWS)

typedef __attribute__((ext_vector_type(8))) short sh8;    // 8 bf16 = 4 VGPR
typedef __attribute__((ext_vector_type(4))) float f32x4;  // MFMA acc

__device__ __forceinline__ float wave_sum64(float v) {
#pragma unroll
    for (int m = 32; m >= 1; m >>= 1) v += __shfl_xor(v, m, 64);
    return v;
}

// RNE float -> bf16 bit trick (inputs finite)
__device__ __forceinline__ unsigned short f2bf(float f) {
    unsigned u = __float_as_uint(f);
    unsigned r = (u + 0x7fffu + ((u >> 16) & 1u)) >> 16;
    return (unsigned short)r;
}
__device__ __forceinline__ float bf2f(unsigned short h) {
    return __uint_as_float(((unsigned)h) << 16);
}

// Fragment layout (unchanged since round 0): frag #((tile16*3+split)*2+khalf)
// is 64 lanes x 16B; element (lane,j) = split_s(src[tile16*16+(lane&15)]
// [khalf*32+(lane>>4)*8+j]). Writer: tile=rc>>4, m=rc&15, h=dim>>5,
// q=(dim>>3)&3, j=dim&7, lane'=q*16+m.

// Kernel 1: code norms + bf16x3 code fragments (bit-identical math to R2-R10)
// + zeroes out_loss (stream order puts this before rq_fused's atomicAdds).
__global__ void rq_prep_codes(const float* __restrict__ codes,
                              float* __restrict__ cn,
                              unsigned short* __restrict__ cfrag,
                              float* __restrict__ out_loss) {
    int tid = threadIdx.x;
    int lane = tid & 63;                 // dim
    int c = blockIdx.x * 4 + (tid >> 6); // code
    if (blockIdx.x == 0 && tid == 0) *out_loss = 0.f;

    float cvv = codes[(size_t)c * DIM + lane];
    float s = wave_sum64(cvv * cvv);
    if (lane == 0) cn[c] = s;

    unsigned short s0 = f2bf(cvv);
    float rr = cvv - bf2f(s0);
    unsigned short s1 = f2bf(rr);
    rr -= bf2f(s1);
    unsigned short s2 = f2bf(rr);

    int ct = c >> 4, m = c & 15;
    int h = lane >> 5, q = (lane >> 3) & 3, j = lane & 7;
    int lanep = q * 16 + m;
    size_t base = ((size_t)(ct * 3) * 2 + h) * 512 + (size_t)lanep * 8 + j;
    cfrag[base] = s0;
    cfrag[base + 2 * 512] = s1;
    cfrag[base + 4 * 512] = s2;
}

// Kernel 2 (FUSED — EXACT round-9 configuration, the verified 83.26 us
// optimum): one block = 32 rows, 8 waves (512 thr), __launch_bounds__(512,2).
// VERIFIED-CLEAN (round-6 counters): VGPR=100, FETCH 6 MB, WRITE 2.1 MB,
// no scratch. Locked-in lessons:
//   R1: no threadfence/last-block protocols (55 us L2-writeback serialize).
//   R3/R7: never force arch-VGPR cap below the live set (spill = 10x);
//          512 thr max for this ~100-VGPR body.
//   R9: graph-node count is free; overhead is fixed (fill + launch).
//   R10: 4-deep prefetch REGRESSES (-4.2 us): +72 VGPR live + guard
//        branches outweigh latency cover at 2 waves/SIMD. The 2-deep
//        ping-pong below is the measured optimum of {1,2,4}-deep.
// P2 sits ~2x above its ~6 us issue/L2 floor, held there by the
// {VGPR cap <-> occupancy <-> L2 latency} triangle (3 mechanisms tried).
__global__ __launch_bounds__(512, 2) void rq_fused(
        const float* __restrict__ x,
        const float* __restrict__ pq,
        const float* __restrict__ codes,
        const float* __restrict__ cn,
        const unsigned short* __restrict__ cfrag,
        float* __restrict__ out_q,
        float* __restrict__ out_idx,
        float* __restrict__ out_loss) {
    __shared__ unsigned short afrag[12 * 512];                 // 12 KB
    __shared__ unsigned long long best[WAVES][ROWS_PER_BLOCK]; // 2 KB
    __shared__ float lpart[WAVES];

    int tid = threadIdx.x;
    int lane = tid & 63;
    int w = tid >> 6;                    // 0..7
    int r0 = blockIdx.x * ROWS_PER_BLOCK;

    float uvr[4], xvr[4], dr[4];

    // ---- P1: prep 4 rows per wave into LDS fragments ----
#pragma unroll
    for (int i = 0; i < 4; ++i) {
        int lr = w * 4 + i;
        int r = r0 + lr;
        float xv = x[(size_t)r * DIM + lane];
        float qv = pq[(size_t)r * DIM + lane];
        float n2 = wave_sum64(qv * qv);
        float inv = 1.0f / fmaxf(sqrtf(n2), EPSF);
        float uv = qv * inv;
        float d = V_VAL * wave_sum64(uv);
        float a = wave_sum64(uv * xv);
        float b = V_VAL * wave_sum64(xv);
        float den = 1.0f + d + EPSF;
        float cu = -b + (d * b - a) / den;
        float cv = a - (b - d * a) / den;
        float xcv = xv + uv * cu + V_VAL * cv;

        uvr[i] = uv; xvr[i] = xv; dr[i] = d;

        unsigned short s0 = f2bf(xcv);
        float rr = xcv - bf2f(s0);
        unsigned short s1 = f2bf(rr);
        rr -= bf2f(s1);
        unsigned short s2 = f2bf(rr);

        int rt = lr >> 4, m = lr & 15;
        int h = lane >> 5, q = (lane >> 3) & 3, j = lane & 7;
        int lanep = q * 16 + m;
        int base = ((rt * 3) * 2 + h) * 512 + lanep * 8 + j;
        afrag[base] = s0;
        afrag[base + 2 * 512] = s1;
        afrag[base + 4 * 512] = s2;
    }

    __syncthreads();

    // ---- P2: distance scan over this wave's 256-code range ----
    const sh8* lf = (const sh8*)afrag;
    const sh8* cf = (const sh8*)cfrag;

    sh8 afr[2][3][2];
#pragma unroll
    for (int rs = 0; rs < 2; ++rs)
#pragma unroll
        for (int s = 0; s < 3; ++s)
#pragma unroll
            for (int h = 0; h < 2; ++h)
                afr[rs][s][h] = lf[((rs * 3 + s) * 2 + h) * 64 + lane];

    int cbase = w * CODES_PER_WAVE;

    float bv[2][4];
    int bi[2][4];
#pragma unroll
    for (int rs = 0; rs < 2; ++rs)
#pragma unroll
        for (int i = 0; i < 4; ++i) { bv[rs][i] = INFINITY; bi[rs][i] = 0x7fffffff; }

    auto loadB = [&](sh8 (&Bf)[3][2], float& cnv, int t) {
        int ct = (cbase >> 4) + t;
#pragma unroll
        for (int s = 0; s < 3; ++s)
#pragma unroll
            for (int h = 0; h < 2; ++h)
                Bf[s][h] = cf[(size_t)((ct * 3 + s) * 2 + h) * 64 + lane];
        cnv = cn[cbase + t * 16 + (lane & 15)];
    };

    auto computeTile = [&](const sh8 (&Bf)[3][2], float cnv, int t) {
        f32x4 accA[2], accB[2];
#pragma unroll
        for (int rs = 0; rs < 2; ++rs) {
            accA[rs] = (f32x4){0.f, 0.f, 0.f, 0.f};
            accB[rs] = (f32x4){0.f, 0.f, 0.f, 0.f};
        }
        // 4 independent chains of depth 6 (2 rowsets x 2 K-halves),
        // smallest-weight products first (order validated rounds 3-10).
#pragma unroll
        for (int rs = 0; rs < 2; ++rs) {
            accA[rs] = __builtin_amdgcn_mfma_f32_16x16x32_bf16(afr[rs][2][0], Bf[0][0], accA[rs], 0, 0, 0);
            accB[rs] = __builtin_amdgcn_mfma_f32_16x16x32_bf16(afr[rs][2][1], Bf[0][1], accB[rs], 0, 0, 0);
            accA[rs] = __builtin_amdgcn_mfma_f32_16x16x32_bf16(afr[rs][1][0], Bf[1][0], accA[rs], 0, 0, 0);
            accB[rs] = __builtin_amdgcn_mfma_f32_16x16x32_bf16(afr[rs][1][1], Bf[1][1], accB[rs], 0, 0, 0);
            accA[rs] = __builtin_amdgcn_mfma_f32_16x16x32_bf16(afr[rs][0][0], Bf[2][0], accA[rs], 0, 0, 0);
            accB[rs] = __builtin_amdgcn_mfma_f32_16x16x32_bf16(afr[rs][0][1], Bf[2][1], accB[rs], 0, 0, 0);
            accA[rs] = __builtin_amdgcn_mfma_f32_16x16x32_bf16(afr[rs][1][0], Bf[0][0], accA[rs], 0, 0, 0);
            accB[rs] = __builtin_amdgcn_mfma_f32_16x16x32_bf16(afr[rs][1][1], Bf[0][1], accB[rs], 0, 0, 0);
            accA[rs] = __builtin_amdgcn_mfma_f32_16x16x32_bf16(afr[rs][0][0], Bf[1][0], accA[rs], 0, 0, 0);
            accB[rs] = __builtin_amdgcn_mfma_f32_16x16x32_bf16(afr[rs][0][1], Bf[1][1], accB[rs], 0, 0, 0);
            accA[rs] = __builtin_amdgcn_mfma_f32_16x16x32_bf16(afr[rs][0][0], Bf[0][0], accA[rs], 0, 0, 0);
            accB[rs] = __builtin_amdgcn_mfma_f32_16x16x32_bf16(afr[rs][0][1], Bf[0][1], accB[rs], 0, 0, 0);
        }
        int idxv = cbase + t * 16 + (lane & 15);
#pragma unroll
        for (int rs = 0; rs < 2; ++rs)
#pragma unroll
            for (int reg = 0; reg < 4; ++reg) {
                float sc = fmaf(-2.0f, accA[rs][reg] + accB[rs][reg], cnv);
                if (sc < bv[rs][reg]) { bv[rs][reg] = sc; bi[rs][reg] = idxv; }
            }
    };

    {
        sh8 bA[3][2], bB[3][2];
        float cnA, cnB;
        loadB(bA, cnA, 0);
#pragma unroll 1
        for (int tt = 0; tt < TILES_PER_WAVE / 2; ++tt) {
            loadB(bB, cnB, 2 * tt + 1);
            computeTile(bA, cnA, 2 * tt);
            if (tt < TILES_PER_WAVE / 2 - 1) loadB(bA, cnA, 2 * tt + 2);
            computeTile(bB, cnB, 2 * tt + 1);
        }
    }

    // Per-row reduction across 16 cols -> this wave's best per local row.
    // row = rs*16 + (lane>>4)*4 + reg.
#pragma unroll
    for (int rs = 0; rs < 2; ++rs) {
#pragma unroll
        for (int reg = 0; reg < 4; ++reg) {
            float v = bv[rs][reg];
            int ix = bi[rs][reg];
#pragma unroll
            for (int m = 1; m < 16; m <<= 1) {
                float ov = __shfl_xor(v, m, 64);
                int oi = __shfl_xor(ix, m, 64);
                if (ov < v || (ov == v && oi < ix)) { v = ov; ix = oi; }
            }
            if ((lane & 15) == reg) {
                int lr = rs * 16 + (lane >> 4) * 4 + reg;
                unsigned u = __float_as_uint(v);
                unsigned k32 = (u & 0x80000000u) ? ~u : (u | 0x80000000u);
                best[w][lr] = ((unsigned long long)k32 << 32) |
                              (unsigned long long)(unsigned)ix;
            }
        }
    }

    __syncthreads();

    // ---- P3: combine 8 wave-partials per row + epilogue + in-block loss ----
    float lsum = 0.f;
#pragma unroll
    for (int i = 0; i < 4; ++i) {
        int lr = w * 4 + i;
        int r = r0 + lr;
        unsigned long long k = best[0][lr];
#pragma unroll
        for (int ww = 1; ww < WAVES; ++ww) {
            unsigned long long o = best[ww][lr];
            if (o < k) k = o;   // ranges w-ascending: global first-occurrence kept
        }
        int idx = (int)(unsigned)(k & 0xFFFFFFFFull);

        float qc = codes[(size_t)idx * DIM + lane];
        float aq = wave_sum64(uvr[i] * qc);
        float bq = V_VAL * wave_sum64(qc);
        float den = 1.0f + dr[i] + EPSF;
        float cu = bq + (dr[i] * bq - aq) / den;
        float cv = -aq - (bq - dr[i] * aq) / den;
        float qout = qc + uvr[i] * cu + V_VAL * cv;
        out_q[(size_t)r * DIM + lane] = qout;

        float diff = xvr[i] - qc;
        lsum += wave_sum64(diff * diff);
        if (lane == 0) out_idx[r] = (float)idx;
    }

    if (lane == 0) lpart[w] = lsum;
    __syncthreads();
    if (tid == 0) {
        float s = 0.f;
#pragma unroll
        for (int ww = 0; ww < WAVES; ++ww) s += lpart[ww];
        atomicAdd(out_loss, s * LOSS_SCALE);  // 256 adds total; no fences
    }
}

extern "C" void kernel_launch(void* const* d_in, const int* in_sizes, int n_in,
                              void* d_out, int out_size, void* d_ws, size_t ws_size,
                              hipStream_t stream) {
    const float* x     = (const float*)d_in[0];
    const float* pq    = (const float*)d_in[1];
    const float* codes = (const float*)d_in[2];

    float* out      = (float*)d_out;
    float* out_q    = out;                         // B*D
    float* out_idx  = out + (size_t)B_ROWS * DIM;  // B
    float* out_loss = out_idx + B_ROWS;            // 1

    char* ws = (char*)d_ws;
    float* cn            = (float*)ws;                          // 8 KB
    unsigned short* cfrg = (unsigned short*)(ws + 1024 * 1024); // 768 KB

    rq_prep_codes<<<NCODES / 4, 256, 0, stream>>>(codes, cn, cfrg, out_loss);
    rq_fused<<<B_ROWS / ROWS_PER_BLOCK, 512, 0, stream>>>(
        x, pq, codes, cn, cfrg, out_q, out_idx, out_loss);
}